// Round 5
// baseline (74.078 us; speedup 1.0000x reference)
//
#include <hip/hip_runtime.h>
#include <hip/hip_bf16.h>

// CTC loss, linear-domain forward recurrence with windowed rescaling.
// One wave per batch item; lane s < 33 owns extended-label state s.
// Memory: per-wave private 3-slot LDS ring of 8-row groups, filled by
// global_load_lds (width 16, fire-and-forget) with counted vmcnt waits —
// 2 groups of lookahead always in flight, no barriers (no cross-wave LDS).

__device__ __forceinline__ float dpp_shr1(float x) {  // lane l <- l-1, lane 0 <- 0
    int r = __builtin_amdgcn_update_dpp(0, __builtin_bit_cast(int, x),
                                        0x138 /*wave_shr:1*/, 0xF, 0xF, true);
    return __builtin_bit_cast(float, r);
}

#define AS1(p) ((const __attribute__((address_space(1))) void*)(p))
#define AS3(p) ((__attribute__((address_space(3))) void*)(p))
#define VMW(n) asm volatile("s_waitcnt vmcnt(" #n ")" ::: "memory")

__global__ __launch_bounds__(256) void ctc_loss_kernel(
    const float* __restrict__ y_pred,
    const int*   __restrict__ labels,
    const int*   __restrict__ input_length,
    const int*   __restrict__ label_length,
    float*       __restrict__ out,
    int Bn)
{
    constexpr int T = 256, C = 96, L = 16;
    constexpr int blank = C - 1;          // 95
    constexpr float EPS = 1e-7f;

    // [wave][ring slot][8 rows x 96 classes]
    __shared__ float smem[4][3][768];

    const int lane = threadIdx.x & 63;
    const int wv   = threadIdx.x >> 6;
    const int b = blockIdx.x * 4 + wv;
    if (b >= Bn) return;                  // wave-uniform; no barriers in kernel

    const int il = input_length[b];
    const int ll = label_length[b];
    const int s  = lane;

    int  extc = blank;
    bool skip_ok = false;
    if (s < 33 && (s & 1)) {
        extc = labels[b * L + (s >> 1)];
        if (s >= 3) skip_ok = (extc != labels[b * L + (s >> 1) - 1]);
    }
    const bool valid = (s < 2 * ll + 1);  // false for s >= 33 too

    const float* gbase = y_pred + (size_t)b * T * C;  // 256 rows x 96 f32

    float a = 0.0f, logC = 0.0f;

    // Stage group grp (8 rows = 3072 B) into ring slot: 3 x 1KB direct-to-LDS.
    auto stage = [&](int grp, int slot) {
        const float* gp = gbase + (size_t)grp * 768 + lane * 4;  // lane*16 B
        float* lp = &smem[wv][slot][0];                          // wave-uniform
        __builtin_amdgcn_global_load_lds(AS1(gp),       AS3(lp),       16, 0, 0);
        __builtin_amdgcn_global_load_lds(AS1(gp + 256), AS3(lp + 256), 16, 0, 0);
        __builtin_amdgcn_global_load_lds(AS1(gp + 512), AS3(lp + 512), 16, 0, 0);
    };

    auto step = [&](float yv, int t) {
        float p1 = dpp_shr1(a);           // zero-fill at lane 0 (bound_ctrl)
        float p2 = dpp_shr1(p1);
        p2 = skip_ok ? p2 : 0.0f;
        float nw = (a + p1 + p2) * yv;
        a = (t < il) ? nw : a;
    };

#define DPPMAX(mv, ctrl)                                                      \
    do { int s_ = __builtin_amdgcn_update_dpp(0, __builtin_bit_cast(int, mv), \
                                              (ctrl), 0xF, 0xF, true);        \
         mv = fmaxf(mv, __builtin_bit_cast(float, s_)); } while (0)

    auto rescale = [&]() {
        a = valid ? a : 0.0f;             // clear upward contamination
        float m = a;
        DPPMAX(m, 0x111); DPPMAX(m, 0x112); DPPMAX(m, 0x114); DPPMAX(m, 0x118);
        DPPMAX(m, 0x142); DPPMAX(m, 0x143);          // lane 63 = wave max
        m = __builtin_bit_cast(float,
                __builtin_amdgcn_readlane(__builtin_bit_cast(int, m), 63));
        logC += __logf(m);
        a *= __builtin_amdgcn_rcpf(m);
    };

    // Process one 8-row group from a ring slot; rescale once per group.
    // 8-step worst-case decay of the max state is >= ~1e-16: far from f32 flush.
    auto proc8 = [&](int t0, int slot, bool first) {
        float z[8];
        #pragma unroll
        for (int r = 0; r < 8; ++r)
            z[r] = smem[wv][slot][r * 96 + extc];   // ds_read, imm offsets
        if (first) a = ((s == 0) | ((s == 1) & (ll >= 1))) ? z[0] : 0.0f;
        else       step(z[0], t0);
        step(z[1], t0 + 1); step(z[2], t0 + 2); step(z[3], t0 + 3);
        step(z[4], t0 + 4); step(z[5], t0 + 5); step(z[6], t0 + 6);
        step(z[7], t0 + 7);
        rescale();
    };

    // Prologue: fill the ring (groups 0..2 of 32).
    stage(0, 0); stage(1, 1); stage(2, 2);

    VMW(6); proc8(0,  0, true );  stage(3, 0);
    VMW(6); proc8(8,  1, false);  stage(4, 1);
    VMW(6); proc8(16, 2, false);  stage(5, 2);

    for (int g = 3; g <= 27; g += 3) {    // groups 3..29; staging stops at 31
        VMW(6); proc8(8 * g,       0, false);  stage(g + 3, 0);
        VMW(6); proc8(8 * (g + 1), 1, false);  stage(g + 4, 1);
        VMW(6); proc8(8 * (g + 2), 2, false);  if (g != 27) stage(g + 5, 2);
    }
    VMW(3); proc8(240, 0, false);         // group 30
    VMW(0); proc8(248, 1, false);         // group 31

    // loss = il*log(1+C*eps) - logC - log(a[2ll] + a[2ll-1])
    const int i_b = 2 * ll;
    const int i_l = (2 * ll - 1 > 0) ? (2 * ll - 1) : 0;
    const float ab = __shfl(a, i_b, 64);
    const float al = __shfl(a, i_l, 64);
    const float p  = (ll > 0) ? (ab + al) : ab;
    const float loss = (float)il * logf(1.0f + (float)C * EPS) - logC - __logf(p);
    if (lane == 0) out[b] = loss;
#undef DPPMAX
}

extern "C" void kernel_launch(void* const* d_in, const int* in_sizes, int n_in,
                              void* d_out, int out_size, void* d_ws, size_t ws_size,
                              hipStream_t stream) {
    const float* y_pred       = (const float*)d_in[0];
    const int*   labels       = (const int*)d_in[1];
    const int*   input_length = (const int*)d_in[2];
    const int*   label_length = (const int*)d_in[3];
    float*       out          = (float*)d_out;

    const int B = in_sizes[2];
    const int blocks = (B + 3) / 4;
    ctc_loss_kernel<<<blocks, 256, 0, stream>>>(y_pred, labels, input_length,
                                                label_length, out, B);
}